// Round 1
// baseline (1800.989 us; speedup 1.0000x reference)
//
#include <hip/hip_runtime.h>

// ---------------------------------------------------------------------------
// GraphNetwork: edge MLP (gather + [E,384]@[384,256] relu @[256,128]) writing
// new_edges only (NO per-element atomics). Segment sums are done by building
// a CSR edge index (histogram -> scan -> scatter) and fusing the gather-sum
// into the node kernel's staging phase. bf16 MFMA throughout.
// ---------------------------------------------------------------------------

typedef unsigned short ushort_t;
typedef __attribute__((ext_vector_type(8))) short bf16x8;
typedef __attribute__((ext_vector_type(4))) float f32x4;

#define MFMA16(a, b, c) __builtin_amdgcn_mfma_f32_16x16x32_bf16(a, b, c, 0, 0, 0)

__device__ __forceinline__ ushort_t f2bf(float f) {
    unsigned int u = __builtin_bit_cast(unsigned int, f);
    u += 0x7fffu + ((u >> 16) & 1u);   // RNE
    return (ushort_t)(u >> 16);
}

// Pack fp32 row-major W[K][N] -> bf16 Wp[((k>>3)*N + n)*8 + (k&7)]
// so a B-fragment (8 consecutive k for fixed n) is one contiguous 16B unit.
__global__ void pack_all(const float* __restrict__ eW1, const float* __restrict__ eW2,
                         const float* __restrict__ nW1, const float* __restrict__ nW2,
                         ushort_t* __restrict__ eW1p, ushort_t* __restrict__ eW2p,
                         ushort_t* __restrict__ nW1p, ushort_t* __restrict__ nW2p) {
    int idx = blockIdx.x * 256 + threadIdx.x;   // total 262144
    const float* W; ushort_t* Wp; int N, local;
    if (idx < 98304)       { W = eW1; Wp = eW1p; N = 256; local = idx; }
    else if (idx < 131072) { W = eW2; Wp = eW2p; N = 128; local = idx - 98304; }
    else if (idx < 229376) { W = nW1; Wp = nW1p; N = 256; local = idx - 131072; }
    else                   { W = nW2; Wp = nW2p; N = 128; local = idx - 229376; }
    int k = local / N;
    int n = local - k * N;
    Wp[((size_t)((k >> 3) * N + n)) * 8 + (k & 7)] = f2bf(W[(size_t)k * N + n]);
}

// ---------------------------------------------------------------------------
// CSR build: histogram -> exclusive scan -> scatter.
// ---------------------------------------------------------------------------
__global__ void hist_kernel(const int* __restrict__ senders, const int* __restrict__ receivers,
                            int* __restrict__ cnt_s, int* __restrict__ cnt_r) {
    int e = blockIdx.x * 256 + threadIdx.x;
    if (e < 600000) {
        atomicAdd(&cnt_s[senders[e]], 1);
        atomicAdd(&cnt_r[receivers[e]], 1);
    }
}

__device__ __forceinline__ int wave_incl_scan(int v, int lane) {
#pragma unroll
    for (int d = 1; d < 64; d <<= 1) {
        int t = __shfl_up(v, d, 64);
        if (lane >= d) v += t;
    }
    return v;
}

// grid=2 (block 0: sender arrays, block 1: receiver arrays), 1024 threads.
// cnt_r = cnt_s + 50000 etc. (contiguous layout).
__global__ void scan_kernel(const int* __restrict__ cnt, int* __restrict__ off,
                            int* __restrict__ cur) {
    const int n = 50000;
    cnt += blockIdx.x * n; off += blockIdx.x * n; cur += blockIdx.x * n;
    const int tid  = threadIdx.x;       // 1024
    const int lane = tid & 63;
    const int wv   = tid >> 6;          // 16 waves
    __shared__ int wsum[16];
    int carry = 0;
    for (int base = 0; base < n; base += 1024) {
        int i = base + tid;
        int v = (i < n) ? cnt[i] : 0;
        int incl = wave_incl_scan(v, lane);
        if (lane == 63) wsum[wv] = incl;
        __syncthreads();
        if (wv == 0 && lane < 16) {
            int s = wsum[lane];
#pragma unroll
            for (int d = 1; d < 16; d <<= 1) {
                int t = __shfl_up(s, d, 64);
                if (lane >= d) s += t;
            }
            wsum[lane] = s;             // inclusive per-wave prefix
        }
        __syncthreads();
        int wbase = (wv == 0) ? 0 : wsum[wv - 1];
        int excl  = carry + wbase + incl - v;
        if (i < n) { off[i] = excl; cur[i] = excl; }
        carry += wsum[15];
        __syncthreads();
    }
}

__global__ void scatter_kernel(const int* __restrict__ senders, const int* __restrict__ receivers,
                               int* __restrict__ cur_s, int* __restrict__ cur_r,
                               int* __restrict__ idx_s, int* __restrict__ idx_r) {
    int e = blockIdx.x * 256 + threadIdx.x;
    if (e < 600000) {
        int p = atomicAdd(&cur_s[senders[e]], 1);
        idx_s[p] = e;
        int q = atomicAdd(&cur_r[receivers[e]], 1);
        idx_r[q] = e;
    }
}

// A-tile: 64 rows x 384 k, bf16, pitch 392 (pad +8 -> 2-way bank pattern, free)
#define APITCH 392
// H-tile: 64 rows x 64 cols (strip), pitch 72
#define HPITCH 72

// ---------------------------------------------------------------------------
// Edge kernel: 64 edges / block, 256 threads (4 waves, each 16 rows).
// Pure gather + MLP + coalesced store; segment sums handled downstream.
// ---------------------------------------------------------------------------
__global__ __launch_bounds__(256, 2)
void edge_kernel(const float* __restrict__ node_feat, const float* __restrict__ edge_feat,
                 const int* __restrict__ senders, const int* __restrict__ receivers,
                 const ushort_t* __restrict__ W1p, const float* __restrict__ b1,
                 const ushort_t* __restrict__ W2p, const float* __restrict__ b2,
                 float* __restrict__ new_edges) {
    __shared__ ushort_t Alds[64 * APITCH];  // 50176 B
    __shared__ ushort_t Wlds[8192];         // 16384 B
    __shared__ ushort_t Hlds[64 * HPITCH];  //  9216 B

    const int tid = threadIdx.x;
    const int ebase = blockIdx.x * 64;

    // ---- gather + f32->bf16 convert: rows = [edge_feat | nf[send] | nf[recv]]
    for (int t = tid; t < 6144; t += 256) {       // 64 rows * 96 float4-pieces
        int row = t / 96;
        int p   = t - row * 96;
        int e   = ebase + row;
        int k0  = p * 4;
        const float* src;
        if (p < 32)      src = edge_feat + (size_t)e * 128 + k0;
        else if (p < 64) src = node_feat + (size_t)senders[e] * 128 + (k0 - 128);
        else             src = node_feat + (size_t)receivers[e] * 128 + (k0 - 256);
        float4 v = *(const float4*)src;
        ushort4 w;
        w.x = f2bf(v.x); w.y = f2bf(v.y); w.z = f2bf(v.z); w.w = f2bf(v.w);
        *(ushort4*)&Alds[row * APITCH + k0] = w;
    }
    __syncthreads();

    const int wv   = tid >> 6;       // wave 0..3 -> rows [wv*16, wv*16+16)
    const int lane = tid & 63;
    const int lrow = lane & 15;
    const int lq   = lane >> 4;
    const int arow = wv * 16 + lrow;

    f32x4 acc2[8];
#pragma unroll
    for (int i = 0; i < 8; i++) acc2[i] = (f32x4){0.f, 0.f, 0.f, 0.f};

#pragma unroll
    for (int s = 0; s < 4; s++) {                 // 4 strips of 64 H-cols
        const int sbase = s * 64;
        f32x4 acc1[4];
#pragma unroll
        for (int i = 0; i < 4; i++) acc1[i] = (f32x4){0.f, 0.f, 0.f, 0.f};

#pragma unroll
        for (int kc = 0; kc < 3; kc++) {          // K chunks of 128
            const int kcb = kc * 128;
            // stage W1 chunk [128k x 64n]: 1024 x 16B units
            for (int u = tid; u < 1024; u += 256) {
                int kq16 = u >> 6;
                int n    = u & 63;
                *(uint4*)&Wlds[u * 8] =
                    *(const uint4*)&W1p[(size_t)(((kcb >> 3) + kq16) * 256 + sbase + n) * 8];
            }
            __syncthreads();
#pragma unroll
            for (int kt = 0; kt < 4; kt++) {
                bf16x8 a = *(const bf16x8*)&Alds[arow * APITCH + kcb + kt * 32 + lq * 8];
#pragma unroll
                for (int nt = 0; nt < 4; nt++) {
                    bf16x8 b = *(const bf16x8*)&Wlds[((kt * 4 + lq) * 64 + nt * 16 + lrow) * 8];
                    acc1[nt] = MFMA16(a, b, acc1[nt]);
                }
            }
            __syncthreads();
        }

        // bias + relu -> bf16 H strip (C layout: col=lane&15, row=lq*4+reg)
#pragma unroll
        for (int nt = 0; nt < 4; nt++) {
            float bb = b1[sbase + nt * 16 + lrow];
#pragma unroll
            for (int rg = 0; rg < 4; rg++) {
                int row = wv * 16 + lq * 4 + rg;
                float v = acc1[nt][rg] + bb;
                v = v > 0.f ? v : 0.f;
                Hlds[row * HPITCH + nt * 16 + lrow] = f2bf(v);
            }
        }
        __syncthreads();

        // stage W2 chunk [64k x 128n]: 1024 x 16B units
        for (int u = tid; u < 1024; u += 256) {
            int kq16 = u >> 7;
            int n    = u & 127;
            *(uint4*)&Wlds[u * 8] = *(const uint4*)&W2p[(size_t)((s * 8 + kq16) * 128 + n) * 8];
        }
        __syncthreads();

        // GEMM2 partial: k in [s*64, s*64+64)
#pragma unroll
        for (int kt = 0; kt < 2; kt++) {
            bf16x8 a = *(const bf16x8*)&Hlds[arow * HPITCH + kt * 32 + lq * 8];
#pragma unroll
            for (int nt = 0; nt < 8; nt++) {
                bf16x8 b = *(const bf16x8*)&Wlds[((kt * 4 + lq) * 128 + nt * 16 + lrow) * 8];
                acc2[nt] = MFMA16(a, b, acc2[nt]);
            }
        }
        __syncthreads();   // Wlds/Hlds reused next strip
    }

    // ---- epilogue: +b2, coalesced write of new_edges (no atomics)
    float bv[8];
#pragma unroll
    for (int nt = 0; nt < 8; nt++) bv[nt] = b2[nt * 16 + lrow];
#pragma unroll
    for (int rg = 0; rg < 4; rg++) {
        int row = wv * 16 + lq * 4 + rg;
        float* er = new_edges + (size_t)(ebase + row) * 128;
#pragma unroll
        for (int nt = 0; nt < 8; nt++) {
            er[nt * 16 + lrow] = acc2[nt][rg] + bv[nt];
        }
    }
}

// ---------------------------------------------------------------------------
// Node kernel: fused CSR gather-sum aggregation + MLP.
// 64 nodes / block; 4 threads per node, each owning 32 of the 128 cols.
// ---------------------------------------------------------------------------
__global__ __launch_bounds__(256, 2)
void node_kernel(const float* __restrict__ node_feat, const float* __restrict__ new_edges,
                 const int* __restrict__ off_s, const int* __restrict__ cnt_s,
                 const int* __restrict__ idx_s,
                 const int* __restrict__ off_r, const int* __restrict__ cnt_r,
                 const int* __restrict__ idx_r,
                 const ushort_t* __restrict__ W1p, const float* __restrict__ b1,
                 const ushort_t* __restrict__ W2p, const float* __restrict__ b2,
                 float* __restrict__ new_nodes) {
    __shared__ ushort_t Alds[64 * APITCH];
    __shared__ ushort_t Wlds[8192];
    __shared__ ushort_t Hlds[64 * HPITCH];

    const int tid = threadIdx.x;
    const int nbase = blockIdx.x * 64;
    const int nrow  = tid >> 2;        // 0..63
    const int tq    = tid & 3;         // column quarter
    const int n     = nbase + nrow;
    const int cbase = tq * 32;         // float-col base within 128

    if (n < 50000) {
        // cols [0,128): node_feat
        const float* nf = node_feat + (size_t)n * 128 + cbase;
#pragma unroll
        for (int i = 0; i < 8; i++) {
            f32x4 v = *(const f32x4*)(nf + i * 4);
            ushort4 w;
            w.x = f2bf(v[0]); w.y = f2bf(v[1]); w.z = f2bf(v[2]); w.w = f2bf(v[3]);
            *(ushort4*)&Alds[nrow * APITCH + cbase + i * 4] = w;
        }
        f32x4 acc[8];
        // cols [128,256): sum of new_edges over sender-CSR
#pragma unroll
        for (int i = 0; i < 8; i++) acc[i] = (f32x4){0.f, 0.f, 0.f, 0.f};
        {
            int j0 = off_s[n], j1 = j0 + cnt_s[n];
            for (int j = j0; j < j1; j++) {
                const float* er = new_edges + (size_t)idx_s[j] * 128 + cbase;
#pragma unroll
                for (int i = 0; i < 8; i++) acc[i] += *(const f32x4*)(er + i * 4);
            }
        }
#pragma unroll
        for (int i = 0; i < 8; i++) {
            ushort4 w;
            w.x = f2bf(acc[i][0]); w.y = f2bf(acc[i][1]);
            w.z = f2bf(acc[i][2]); w.w = f2bf(acc[i][3]);
            *(ushort4*)&Alds[nrow * APITCH + 128 + cbase + i * 4] = w;
        }
        // cols [256,384): sum over receiver-CSR
#pragma unroll
        for (int i = 0; i < 8; i++) acc[i] = (f32x4){0.f, 0.f, 0.f, 0.f};
        {
            int j0 = off_r[n], j1 = j0 + cnt_r[n];
            for (int j = j0; j < j1; j++) {
                const float* er = new_edges + (size_t)idx_r[j] * 128 + cbase;
#pragma unroll
                for (int i = 0; i < 8; i++) acc[i] += *(const f32x4*)(er + i * 4);
            }
        }
#pragma unroll
        for (int i = 0; i < 8; i++) {
            ushort4 w;
            w.x = f2bf(acc[i][0]); w.y = f2bf(acc[i][1]);
            w.z = f2bf(acc[i][2]); w.w = f2bf(acc[i][3]);
            *(ushort4*)&Alds[nrow * APITCH + 256 + cbase + i * 4] = w;
        }
    } else {
        ushort4 z = {0, 0, 0, 0};
#pragma unroll
        for (int i = 0; i < 8; i++) {
            *(ushort4*)&Alds[nrow * APITCH + cbase + i * 4] = z;
            *(ushort4*)&Alds[nrow * APITCH + 128 + cbase + i * 4] = z;
            *(ushort4*)&Alds[nrow * APITCH + 256 + cbase + i * 4] = z;
        }
    }
    __syncthreads();

    const int wv   = tid >> 6;
    const int lane = tid & 63;
    const int lrow = lane & 15;
    const int lq   = lane >> 4;
    const int arow = wv * 16 + lrow;

    f32x4 acc2[8];
#pragma unroll
    for (int i = 0; i < 8; i++) acc2[i] = (f32x4){0.f, 0.f, 0.f, 0.f};

#pragma unroll
    for (int s = 0; s < 4; s++) {
        const int sbase = s * 64;
        f32x4 acc1[4];
#pragma unroll
        for (int i = 0; i < 4; i++) acc1[i] = (f32x4){0.f, 0.f, 0.f, 0.f};

#pragma unroll
        for (int kc = 0; kc < 3; kc++) {
            const int kcb = kc * 128;
            for (int u = tid; u < 1024; u += 256) {
                int kq16 = u >> 6;
                int nn   = u & 63;
                *(uint4*)&Wlds[u * 8] =
                    *(const uint4*)&W1p[(size_t)(((kcb >> 3) + kq16) * 256 + sbase + nn) * 8];
            }
            __syncthreads();
#pragma unroll
            for (int kt = 0; kt < 4; kt++) {
                bf16x8 a = *(const bf16x8*)&Alds[arow * APITCH + kcb + kt * 32 + lq * 8];
#pragma unroll
                for (int nt = 0; nt < 4; nt++) {
                    bf16x8 b = *(const bf16x8*)&Wlds[((kt * 4 + lq) * 64 + nt * 16 + lrow) * 8];
                    acc1[nt] = MFMA16(a, b, acc1[nt]);
                }
            }
            __syncthreads();
        }

#pragma unroll
        for (int nt = 0; nt < 4; nt++) {
            float bb = b1[sbase + nt * 16 + lrow];
#pragma unroll
            for (int rg = 0; rg < 4; rg++) {
                int row = wv * 16 + lq * 4 + rg;
                float v = acc1[nt][rg] + bb;
                v = v > 0.f ? v : 0.f;
                Hlds[row * HPITCH + nt * 16 + lrow] = f2bf(v);
            }
        }
        __syncthreads();

        for (int u = tid; u < 1024; u += 256) {
            int kq16 = u >> 7;
            int nn   = u & 127;
            *(uint4*)&Wlds[u * 8] = *(const uint4*)&W2p[(size_t)((s * 8 + kq16) * 128 + nn) * 8];
        }
        __syncthreads();

#pragma unroll
        for (int kt = 0; kt < 2; kt++) {
            bf16x8 a = *(const bf16x8*)&Hlds[arow * HPITCH + kt * 32 + lq * 8];
#pragma unroll
            for (int nt = 0; nt < 8; nt++) {
                bf16x8 b = *(const bf16x8*)&Wlds[((kt * 4 + lq) * 128 + nt * 16 + lrow) * 8];
                acc2[nt] = MFMA16(a, b, acc2[nt]);
            }
        }
        __syncthreads();
    }

    float bv[8];
#pragma unroll
    for (int nt = 0; nt < 8; nt++) bv[nt] = b2[nt * 16 + lrow];
#pragma unroll
    for (int rg = 0; rg < 4; rg++) {
        int row = wv * 16 + lq * 4 + rg;
        int nn  = nbase + row;
        if (nn < 50000) {
            float* out = new_nodes + (size_t)nn * 128;
#pragma unroll
            for (int nt = 0; nt < 8; nt++) {
                out[nt * 16 + lrow] = acc2[nt][rg] + bv[nt];
            }
        }
    }
}

// ---------------------------------------------------------------------------
extern "C" void kernel_launch(void* const* d_in, const int* in_sizes, int n_in,
                              void* d_out, int out_size, void* d_ws, size_t ws_size,
                              hipStream_t stream) {
    const float* node_feat = (const float*)d_in[0];
    const float* edge_feat = (const float*)d_in[1];
    const int*   senders   = (const int*)d_in[2];
    const int*   receivers = (const int*)d_in[3];
    const float* eW1 = (const float*)d_in[4];
    const float* eb1 = (const float*)d_in[5];
    const float* eW2 = (const float*)d_in[6];
    const float* eb2 = (const float*)d_in[7];
    const float* nW1 = (const float*)d_in[8];
    const float* nb1 = (const float*)d_in[9];
    const float* nW2 = (const float*)d_in[10];
    const float* nb2 = (const float*)d_in[11];

    float* new_nodes = (float*)d_out;                 // 50000*128
    float* new_edges = (float*)d_out + 6400000;       // 600000*128

    // ws layout (ints): cnt_s|cnt_r|off_s|off_r|cur_s|cur_r|idx_s|idx_r, then packed weights
    int* cnt_s = (int*)d_ws;             // 50000
    int* cnt_r = cnt_s + 50000;          // 50000
    int* off_s = cnt_s + 100000;         // 50000
    int* off_r = cnt_s + 150000;         // 50000
    int* cur_s = cnt_s + 200000;         // 50000
    int* cur_r = cnt_s + 250000;         // 50000
    int* idx_s = cnt_s + 300000;         // 600000
    int* idx_r = cnt_s + 900000;         // 600000 -> ends at 6,000,000 B
    ushort_t* eW1p = (ushort_t*)((char*)d_ws + 6000000);
    ushort_t* eW2p = eW1p + 98304;
    ushort_t* nW1p = eW2p + 32768;
    ushort_t* nW2p = nW1p + 98304;

    hipMemsetAsync(d_ws, 0, 400000, stream);          // zero histograms only
    pack_all<<<1024, 256, 0, stream>>>(eW1, eW2, nW1, nW2, eW1p, eW2p, nW1p, nW2p);
    hist_kernel<<<2344, 256, 0, stream>>>(senders, receivers, cnt_s, cnt_r);
    scan_kernel<<<2, 1024, 0, stream>>>(cnt_s, off_s, cur_s);
    scatter_kernel<<<2344, 256, 0, stream>>>(senders, receivers, cur_s, cur_r, idx_s, idx_r);
    edge_kernel<<<9375, 256, 0, stream>>>(node_feat, edge_feat, senders, receivers,
                                          eW1p, eb1, eW2p, eb2, new_edges);
    node_kernel<<<782, 256, 0, stream>>>(node_feat, new_edges,
                                         off_s, cnt_s, idx_s, off_r, cnt_r, idx_r,
                                         nW1p, nb1, nW2p, nb2, new_nodes);
}